// Round 1
// baseline (351.288 us; speedup 1.0000x reference)
//
#include <hip/hip_runtime.h>

#define SEQ 2048
#define EMB 100
#define BOT 5
#define HSIZE 4096          // power of two, >= 2*SEQ for <=50% load factor
#define NTHREADS 256

__global__ __launch_bounds__(NTHREADS) void doc_model_kernel(
    const int* __restrict__ x,
    const float* __restrict__ we,
    const float* __restrict__ idf,
    const float* __restrict__ fc1w,
    const float* __restrict__ fc1b,
    const float* __restrict__ fc2w,
    const float* __restrict__ fc2b,
    float* __restrict__ out)
{
    __shared__ int   hkey[HSIZE];
    __shared__ int   hcnt[HSIZE];
    __shared__ int   ukey[SEQ];
    __shared__ float ucoef[SEQ];
    __shared__ float part[2][EMB];
    __shared__ float red[4];
    __shared__ float hsh[BOT];
    __shared__ int   nuniq;
    __shared__ float zsh;

    const int b   = blockIdx.x;
    const int tid = threadIdx.x;

    // ---- init hash table ----
    for (int i = tid; i < HSIZE; i += NTHREADS) { hkey[i] = -1; hcnt[i] = 0; }
    if (tid == 0) nuniq = 0;
    __syncthreads();

    // ---- build per-row token histogram in LDS hash ----
    const int* xrow = x + (size_t)b * SEQ;
    for (int s = tid; s < SEQ; s += NTHREADS) {
        int key = xrow[s];
        unsigned slot = ((unsigned)key * 2654435761u) >> 20;  // top 12 bits
        for (;;) {
            int prev = atomicCAS(&hkey[slot], -1, key);
            if (prev == -1 || prev == key) { atomicAdd(&hcnt[slot], 1); break; }
            slot = (slot + 1) & (HSIZE - 1);
        }
    }
    __syncthreads();

    // ---- Z = sum cnt*idf, and compact occupied slots -> (key, cnt^2*idf) ----
    float z = 0.0f;
    for (int i = tid; i < HSIZE; i += NTHREADS) {
        int k = hkey[i];
        if (k >= 0) {
            float c = (float)hcnt[i];
            float w = idf[k];
            z += c * w;
            int pos = atomicAdd(&nuniq, 1);
            ukey[pos]  = k;
            ucoef[pos] = c * c * w;
        }
    }
    // block-reduce z (wave64 shuffle, then 4 partials)
    for (int off = 32; off > 0; off >>= 1) z += __shfl_down(z, off);
    if ((tid & 63) == 0) red[tid >> 6] = z;
    __syncthreads();
    if (tid == 0) zsh = red[0] + red[1] + red[2] + red[3];
    __syncthreads();

    const float invZ = 1.0f / zsh;
    const int   nu   = nuniq;

    // ---- doc[e] = invZ * sum_i ucoef[i] * we[ukey[i]][e] ----
    // 2 groups of 128 lanes; lanes 0..99 of each group own a dim.
    const int g = tid >> 7;      // 0 or 1
    const int e = tid & 127;
    if (e < EMB) {
        float acc = 0.0f;
        for (int i = g; i < nu; i += 2) {
            acc += ucoef[i] * we[(size_t)ukey[i] * EMB + e];
        }
        part[g][e] = acc;
    }
    __syncthreads();

    if (tid < EMB) {
        part[0][tid] = (part[0][tid] + part[1][tid]) * invZ;  // doc vector
    }
    __syncthreads();

    // ---- tiny MLP: 100 -> 5 -> 100 ----
    if (tid < BOT) {
        float h = fc1b[tid];
        const float* wrow = fc1w + tid * EMB;
        for (int ei = 0; ei < EMB; ++ei) h += part[0][ei] * wrow[ei];
        hsh[tid] = h;
    }
    __syncthreads();

    if (tid < EMB) {
        float o = fc2b[tid];
        const float* wrow = fc2w + tid * BOT;
        #pragma unroll
        for (int j = 0; j < BOT; ++j) o += hsh[j] * wrow[j];
        out[(size_t)b * EMB + tid] = o;
    }
}

extern "C" void kernel_launch(void* const* d_in, const int* in_sizes, int n_in,
                              void* d_out, int out_size, void* d_ws, size_t ws_size,
                              hipStream_t stream) {
    const int*   x    = (const int*)d_in[0];
    const float* we   = (const float*)d_in[1];
    const float* idf  = (const float*)d_in[2];
    const float* fc1w = (const float*)d_in[3];
    const float* fc1b = (const float*)d_in[4];
    const float* fc2w = (const float*)d_in[5];
    const float* fc2b = (const float*)d_in[6];
    float*       out  = (float*)d_out;

    const int B = in_sizes[0] / SEQ;  // 128
    doc_model_kernel<<<B, NTHREADS, 0, stream>>>(x, we, idf, fc1w, fc1b, fc2w, fc2b, out);
}

// Round 2
// 125.048 us; speedup vs baseline: 2.8092x; 2.8092x over previous
//
#include <hip/hip_runtime.h>

#define SEQ 2048
#define EMB 100
#define BOT 5
#define HSIZE 4096          // power of two, >= 2*SEQ for <=50% load factor
#define SPLIT 16            // gather blocks per row

// ---------------- K1: per-row histogram + compact list ----------------
__global__ __launch_bounds__(512) void k1_hist(
    const int* __restrict__ x, const float* __restrict__ idf,
    int* __restrict__ nuniq, int* __restrict__ gkey, float* __restrict__ gcoef)
{
    __shared__ int   hkey[HSIZE];
    __shared__ int   hcnt[HSIZE];
    __shared__ float red[8];
    __shared__ int   nu;
    __shared__ float zinv;

    const int b = blockIdx.x, tid = threadIdx.x;

    for (int i = tid; i < HSIZE; i += 512) { hkey[i] = -1; hcnt[i] = 0; }
    if (tid == 0) nu = 0;
    __syncthreads();

    const int* xrow = x + (size_t)b * SEQ;
    float z = 0.0f;
    for (int s = tid; s < SEQ; s += 512) {
        int key = xrow[s];
        z += idf[key];                       // Z = sum_s idf[x_s]  (== sum_v cnt*idf)
        unsigned slot = ((unsigned)key * 2654435761u) >> 20;
        for (;;) {
            int prev = atomicCAS(&hkey[slot], -1, key);
            if (prev == -1 || prev == key) { atomicAdd(&hcnt[slot], 1); break; }
            slot = (slot + 1) & (HSIZE - 1);
        }
    }
    // block-reduce z (8 waves)
    for (int off = 32; off > 0; off >>= 1) z += __shfl_down(z, off);
    if ((tid & 63) == 0) red[tid >> 6] = z;
    __syncthreads();
    if (tid == 0) {
        float t = 0.0f;
        #pragma unroll
        for (int i = 0; i < 8; ++i) t += red[i];
        zinv = 1.0f / t;
    }
    __syncthreads();
    const float iz = zinv;

    for (int i = tid; i < HSIZE; i += 512) {
        int k = hkey[i];
        if (k >= 0) {
            float c = (float)hcnt[i];
            int pos = atomicAdd(&nu, 1);
            gkey [b * SEQ + pos] = k;
            gcoef[b * SEQ + pos] = c * c * idf[k] * iz;
        }
    }
    __syncthreads();
    if (tid == 0) nuniq[b] = nu;
}

// ---------------- K2: sliced weighted-embedding gather ----------------
__global__ __launch_bounds__(256) void k2_gather(
    const int* __restrict__ nuniq, const int* __restrict__ gkey,
    const float* __restrict__ gcoef, const float* __restrict__ we,
    float* __restrict__ partial)
{
    __shared__ float part[2][EMB];

    const int bx  = blockIdx.x;
    const int b   = bx >> 4;              // SPLIT == 16
    const int s   = bx & (SPLIT - 1);
    const int tid = threadIdx.x;
    const int g   = tid >> 7;             // 0 or 1
    const int e   = tid & 127;

    const int nu = nuniq[b];
    const int*   kk = gkey  + (size_t)b * SEQ;
    const float* cc = gcoef + (size_t)b * SEQ;

    if (e < EMB) {
        float acc = 0.0f;
        for (int i = s * 2 + g; i < nu; i += SPLIT * 2) {
            acc += cc[i] * we[(size_t)kk[i] * EMB + e];
        }
        part[g][e] = acc;
    }
    __syncthreads();
    if (tid < EMB) partial[(size_t)bx * EMB + tid] = part[0][tid] + part[1][tid];
}

// ---------------- K3: reduce partials + tiny MLP ----------------
__global__ __launch_bounds__(128) void k3_mlp(
    const float* __restrict__ partial,
    const float* __restrict__ fc1w, const float* __restrict__ fc1b,
    const float* __restrict__ fc2w, const float* __restrict__ fc2b,
    float* __restrict__ out)
{
    __shared__ float doc[EMB];
    __shared__ float hsh[BOT];

    const int b = blockIdx.x, tid = threadIdx.x;

    if (tid < EMB) {
        float a = 0.0f;
        const float* p = partial + (size_t)b * SPLIT * EMB + tid;
        #pragma unroll
        for (int s = 0; s < SPLIT; ++s) a += p[s * EMB];
        doc[tid] = a;
    }
    __syncthreads();

    if (tid < BOT) {
        float h = fc1b[tid];
        const float* wr = fc1w + tid * EMB;
        for (int e = 0; e < EMB; ++e) h += doc[e] * wr[e];
        hsh[tid] = h;
    }
    __syncthreads();

    if (tid < EMB) {
        float o = fc2b[tid];
        const float* wr = fc2w + tid * BOT;
        #pragma unroll
        for (int j = 0; j < BOT; ++j) o += hsh[j] * wr[j];
        out[(size_t)b * EMB + tid] = o;
    }
}

extern "C" void kernel_launch(void* const* d_in, const int* in_sizes, int n_in,
                              void* d_out, int out_size, void* d_ws, size_t ws_size,
                              hipStream_t stream) {
    const int*   x    = (const int*)d_in[0];
    const float* we   = (const float*)d_in[1];
    const float* idf  = (const float*)d_in[2];
    const float* fc1w = (const float*)d_in[3];
    const float* fc1b = (const float*)d_in[4];
    const float* fc2w = (const float*)d_in[5];
    const float* fc2b = (const float*)d_in[6];
    float*       out  = (float*)d_out;

    const int B = in_sizes[0] / SEQ;  // 128

    // workspace layout (all 256B-aligned)
    char* ws = (char*)d_ws;
    int*   nuniq   = (int*)ws;                               // B ints
    int*   gkey    = (int*)(ws + 1024);                      // B*SEQ ints   (1 MB)
    float* gcoef   = (float*)(ws + 1024 + (size_t)B*SEQ*4);  // B*SEQ floats (1 MB)
    float* partial = (float*)(ws + 1024 + (size_t)B*SEQ*8);  // B*SPLIT*EMB floats

    k1_hist  <<<B,         512, 0, stream>>>(x, idf, nuniq, gkey, gcoef);
    k2_gather<<<B * SPLIT, 256, 0, stream>>>(nuniq, gkey, gcoef, we, partial);
    k3_mlp   <<<B,         128, 0, stream>>>(partial, fc1w, fc1b, fc2w, fc2b, out);
}